// Round 8
// baseline (1020.456 us; speedup 1.0000x reference)
//
#include <hip/hip_runtime.h>

#define ROWS 131072
#define DD   256
#define MM   512
#define XSTR 264   // x/mr tile row stride (shorts): 256 + 8 pad
#define PSTR 520   // P tile row stride (shorts): 512 + 8 pad

typedef __attribute__((ext_vector_type(8))) short v8s;
typedef __attribute__((ext_vector_type(4))) float v4f;

static __device__ __forceinline__ unsigned short f2bf(float f) {
  union { float f; unsigned int u; } c; c.f = f;
  unsigned int u = c.u;
  return (unsigned short)((u + 0x7fffu + ((u >> 16) & 1u)) >> 16);  // RNE
}
static __device__ __forceinline__ float bf2f(unsigned short h) {
  union { float f; unsigned int u; } c; c.u = ((unsigned int)h) << 16;
  return c.f;
}

// Prep: memory -> bf16 hi/lo [512x256], memT hi [256x512]; Wg -> W1b/W2b [256x256] bf16.
__global__ void vm_prep(const float* __restrict__ mem, const float* __restrict__ Wg,
                        unsigned short* __restrict__ mh, unsigned short* __restrict__ ml,
                        unsigned short* __restrict__ mT, unsigned short* __restrict__ W1b,
                        unsigned short* __restrict__ W2b) {
  int i = blockIdx.x * 256 + threadIdx.x;  // 0..131071
  float v = mem[i];
  unsigned short h = f2bf(v);
  mh[i] = h;
  ml[i] = f2bf(v - bf2f(h));
  int m = i >> 8, d = i & 255;
  mT[d * MM + m] = h;
  float wv = Wg[i];
  int e = i >> 9, c = i & 511;
  unsigned short wb = f2bf(wv);
  if (c < DD) W1b[e * DD + c] = wb;
  else        W2b[e * DD + (c - DD)] = wb;
}

// Kernel A: sim (split-bf16 MFMA) -> softmax -> out_w.  512 thr (8 waves), 32 rows/block.
// Wave w owns sim cols [w*64, w*64+64). Lean: 3 barriers, LDS 35.9KB, reg target <=85
// (launch_bounds 512,6 -> 3 blocks/CU, 24 waves). R7 diagnosis: fused 9-barrier chain was
// the wall; split kernels rely on cross-block TLP instead of compiler-defeated ILP.
__global__ __launch_bounds__(512, 6) void vm_sim(
    const float* __restrict__ x,
    const unsigned short* __restrict__ mh, const unsigned short* __restrict__ ml,
    float* __restrict__ out_w)
{
  __shared__ __align__(16) unsigned short sm_xh[32 * XSTR];
  __shared__ __align__(16) unsigned short sm_xl[32 * XSTR];
  __shared__ __align__(16) float sm_max[32 * 8];
  __shared__ __align__(16) float sm_sum[32 * 8];

  const int tid  = threadIdx.x;
  const int w    = tid >> 6;
  const int lane = tid & 63;
  const int q    = lane >> 4;
  const int n    = lane & 15;
  const long R0  = (long)blockIdx.x * 32;

  // ---- stage x tile rows as bf16 hi/lo ----
  {
    const int row = tid >> 4;
    const int g   = tid & 15;
    const float* xr = x + (R0 + row) * (long)DD;
    const int c0 = g * 16;
    float4 a0 = *(const float4*)(xr + c0);
    float4 a1 = *(const float4*)(xr + c0 + 4);
    float4 a2 = *(const float4*)(xr + c0 + 8);
    float4 a3 = *(const float4*)(xr + c0 + 12);
    float vv[16] = {a0.x,a0.y,a0.z,a0.w, a1.x,a1.y,a1.z,a1.w,
                    a2.x,a2.y,a2.z,a2.w, a3.x,a3.y,a3.z,a3.w};
    v8s hv0, lv0, hv1, lv1;
#pragma unroll
    for (int j = 0; j < 8; ++j) {
      unsigned short h = f2bf(vv[j]);
      hv0[j] = (short)h;
      lv0[j] = (short)f2bf(vv[j] - bf2f(h));
      unsigned short h2 = f2bf(vv[j + 8]);
      hv1[j] = (short)h2;
      lv1[j] = (short)f2bf(vv[j + 8] - bf2f(h2));
    }
    *(v8s*)&sm_xh[row * XSTR + c0]     = hv0;
    *(v8s*)&sm_xh[row * XSTR + c0 + 8] = hv1;
    *(v8s*)&sm_xl[row * XSTR + c0]     = lv0;
    *(v8s*)&sm_xl[row * XSTR + c0 + 8] = lv1;
  }
  __syncthreads();

  // ---- GEMM1: S[32 x 64] = x . mem^T, 3-term bf16 split ----
  v4f acc[2][4];
#pragma unroll
  for (int mt = 0; mt < 2; ++mt)
#pragma unroll
    for (int nt = 0; nt < 4; ++nt) { acc[mt][nt][0]=0.f; acc[mt][nt][1]=0.f; acc[mt][nt][2]=0.f; acc[mt][nt][3]=0.f; }

  for (int ki = 0; ki < 8; ++ki) {
    const int c0 = ki * 32 + q * 8;
    v8s ah[2], al[2];
#pragma unroll
    for (int mt = 0; mt < 2; ++mt) {
      ah[mt] = *(const v8s*)&sm_xh[(mt * 16 + n) * XSTR + c0];
      al[mt] = *(const v8s*)&sm_xl[(mt * 16 + n) * XSTR + c0];
    }
#pragma unroll
    for (int nt = 0; nt < 4; ++nt) {
      const int mrow = w * 64 + nt * 16 + n;
      v8s bh = *(const v8s*)(mh + mrow * DD + c0);
      v8s bl = *(const v8s*)(ml + mrow * DD + c0);
#pragma unroll
      for (int mt = 0; mt < 2; ++mt) {
        acc[mt][nt] = __builtin_amdgcn_mfma_f32_16x16x32_bf16(ah[mt], bh, acc[mt][nt], 0, 0, 0);
        acc[mt][nt] = __builtin_amdgcn_mfma_f32_16x16x32_bf16(al[mt], bh, acc[mt][nt], 0, 0, 0);
        acc[mt][nt] = __builtin_amdgcn_mfma_f32_16x16x32_bf16(ah[mt], bl, acc[mt][nt], 0, 0, 0);
      }
    }
  }

  // ---- softmax over M=512 ----
  float rmax[2][4];
#pragma unroll
  for (int mt = 0; mt < 2; ++mt)
#pragma unroll
    for (int reg = 0; reg < 4; ++reg) {
      float mval = acc[mt][0][reg];
#pragma unroll
      for (int nt = 1; nt < 4; ++nt) mval = fmaxf(mval, acc[mt][nt][reg]);
      rmax[mt][reg] = mval;
    }
#pragma unroll
  for (int off = 1; off < 16; off <<= 1)
#pragma unroll
    for (int mt = 0; mt < 2; ++mt)
#pragma unroll
      for (int reg = 0; reg < 4; ++reg)
        rmax[mt][reg] = fmaxf(rmax[mt][reg], __shfl_xor(rmax[mt][reg], off, 64));
  if (n == 0) {
#pragma unroll
    for (int mt = 0; mt < 2; ++mt)
#pragma unroll
      for (int reg = 0; reg < 4; ++reg)
        sm_max[(mt * 16 + q * 4 + reg) * 8 + w] = rmax[mt][reg];
  }
  __syncthreads();
  float gmax[2][4];
#pragma unroll
  for (int mt = 0; mt < 2; ++mt)
#pragma unroll
    for (int reg = 0; reg < 4; ++reg) {
      v4f r4 = *(const v4f*)&sm_max[(mt * 16 + q * 4 + reg) * 8];
      v4f r5 = *(const v4f*)&sm_max[(mt * 16 + q * 4 + reg) * 8 + 4];
      gmax[mt][reg] = fmaxf(fmaxf(fmaxf(r4[0], r4[1]), fmaxf(r4[2], r4[3])),
                            fmaxf(fmaxf(r5[0], r5[1]), fmaxf(r5[2], r5[3])));
    }
  float rsum[2][4];
#pragma unroll
  for (int mt = 0; mt < 2; ++mt)
#pragma unroll
    for (int reg = 0; reg < 4; ++reg) rsum[mt][reg] = 0.f;
#pragma unroll
  for (int mt = 0; mt < 2; ++mt)
#pragma unroll
    for (int nt = 0; nt < 4; ++nt)
#pragma unroll
      for (int reg = 0; reg < 4; ++reg) {
        float p = __expf(acc[mt][nt][reg] - gmax[mt][reg]);
        acc[mt][nt][reg] = p;
        rsum[mt][reg] += p;
      }
#pragma unroll
  for (int off = 1; off < 16; off <<= 1)
#pragma unroll
    for (int mt = 0; mt < 2; ++mt)
#pragma unroll
      for (int reg = 0; reg < 4; ++reg)
        rsum[mt][reg] += __shfl_xor(rsum[mt][reg], off, 64);
  if (n == 0) {
#pragma unroll
    for (int mt = 0; mt < 2; ++mt)
#pragma unroll
      for (int reg = 0; reg < 4; ++reg)
        sm_sum[(mt * 16 + q * 4 + reg) * 8 + w] = rsum[mt][reg];
  }
  __syncthreads();
#pragma unroll
  for (int mt = 0; mt < 2; ++mt)
#pragma unroll
    for (int reg = 0; reg < 4; ++reg) {
      v4f s4 = *(const v4f*)&sm_sum[(mt * 16 + q * 4 + reg) * 8];
      v4f s5 = *(const v4f*)&sm_sum[(mt * 16 + q * 4 + reg) * 8 + 4];
      const float ginv = 1.0f / (s4[0] + s4[1] + s4[2] + s4[3] + s5[0] + s5[1] + s5[2] + s5[3]);
      const int row = mt * 16 + q * 4 + reg;
#pragma unroll
      for (int nt = 0; nt < 4; ++nt) {
        const int col = w * 64 + nt * 16 + n;
        __builtin_nontemporal_store(acc[mt][nt][reg] * ginv,
                                    &out_w[(R0 + row) * (long)MM + col]);
      }
    }
}

// Kernel B: read P (= out_w), mr = P.mem, gate = sigmoid(x.W1^T + mr.W2^T + bg),
// out_e = x + gate*mr.  512 thr, 32 rows/block, waves own d/e cols [w*32, w*32+32).
// LDS 50.2KB (sm_p 33.3 + sm_xh 16.9; mr aliases sm_p after GEMM2) -> 3 blocks/CU.
// NOTE: out_e PLAIN store (NT on out_e failed post-timing re-poison, Round 3).
__global__ __launch_bounds__(512, 6) void vm_rd(
    const float* __restrict__ x, const float* __restrict__ bg,
    const unsigned short* __restrict__ mT, const unsigned short* __restrict__ W1b,
    const unsigned short* __restrict__ W2b,
    const float* __restrict__ out_w, float* __restrict__ out_e)
{
  __shared__ __align__(16) unsigned short sm_p [32 * PSTR];  // P (PSTR) -> later mr (XSTR)
  __shared__ __align__(16) unsigned short sm_xh[32 * XSTR];
  unsigned short* sm_mr = sm_p;

  const int tid  = threadIdx.x;
  const int w    = tid >> 6;
  const int lane = tid & 63;
  const int q    = lane >> 4;
  const int n    = lane & 15;
  const long R0  = (long)blockIdx.x * 32;

  // ---- stage: P rows (f32 -> bf16) and x rows (hi bf16) ----
  {
    const int row = tid >> 4;
    const int g   = tid & 15;
    const float* pr = out_w + (R0 + row) * (long)MM;
    const int cp = g * 32;
#pragma unroll
    for (int jj = 0; jj < 4; ++jj) {
      float4 a = *(const float4*)(pr + cp + jj * 8);
      float4 b = *(const float4*)(pr + cp + jj * 8 + 4);
      v8s pv;
      pv[0]=(short)f2bf(a.x); pv[1]=(short)f2bf(a.y); pv[2]=(short)f2bf(a.z); pv[3]=(short)f2bf(a.w);
      pv[4]=(short)f2bf(b.x); pv[5]=(short)f2bf(b.y); pv[6]=(short)f2bf(b.z); pv[7]=(short)f2bf(b.w);
      *(v8s*)&sm_p[row * PSTR + cp + jj * 8] = pv;
    }
    const float* xr = x + (R0 + row) * (long)DD;
    const int cx = g * 16;
    float4 a0 = *(const float4*)(xr + cx);
    float4 a1 = *(const float4*)(xr + cx + 4);
    float4 a2 = *(const float4*)(xr + cx + 8);
    float4 a3 = *(const float4*)(xr + cx + 12);
    v8s h0, h1;
    h0[0]=(short)f2bf(a0.x); h0[1]=(short)f2bf(a0.y); h0[2]=(short)f2bf(a0.z); h0[3]=(short)f2bf(a0.w);
    h0[4]=(short)f2bf(a1.x); h0[5]=(short)f2bf(a1.y); h0[6]=(short)f2bf(a1.z); h0[7]=(short)f2bf(a1.w);
    h1[0]=(short)f2bf(a2.x); h1[1]=(short)f2bf(a2.y); h1[2]=(short)f2bf(a2.z); h1[3]=(short)f2bf(a2.w);
    h1[4]=(short)f2bf(a3.x); h1[5]=(short)f2bf(a3.y); h1[6]=(short)f2bf(a3.z); h1[7]=(short)f2bf(a3.w);
    *(v8s*)&sm_xh[row * XSTR + cx]     = h0;
    *(v8s*)&sm_xh[row * XSTR + cx + 8] = h1;
  }
  __syncthreads();

  // ---- GEMM2: mr[32 x 32(d of this wave)] = P . mem, K=512 ----
  v4f acc2[2][2];
#pragma unroll
  for (int mt = 0; mt < 2; ++mt)
#pragma unroll
    for (int nt = 0; nt < 2; ++nt) { acc2[mt][nt][0]=0.f; acc2[mt][nt][1]=0.f; acc2[mt][nt][2]=0.f; acc2[mt][nt][3]=0.f; }

  for (int ki = 0; ki < 16; ++ki) {
    const int c0 = ki * 32 + q * 8;
    v8s pa[2];
#pragma unroll
    for (int mt = 0; mt < 2; ++mt)
      pa[mt] = *(const v8s*)&sm_p[(mt * 16 + n) * PSTR + c0];
#pragma unroll
    for (int nt = 0; nt < 2; ++nt) {
      v8s bt = *(const v8s*)(mT + (w * 32 + nt * 16 + n) * MM + c0);
#pragma unroll
      for (int mt = 0; mt < 2; ++mt)
        acc2[mt][nt] = __builtin_amdgcn_mfma_f32_16x16x32_bf16(pa[mt], bt, acc2[mt][nt], 0, 0, 0);
    }
  }

  // ---- stage mr (bf16) into the P region (P dead) ----
  __syncthreads();
#pragma unroll
  for (int mt = 0; mt < 2; ++mt)
#pragma unroll
    for (int nt = 0; nt < 2; ++nt)
#pragma unroll
      for (int reg = 0; reg < 4; ++reg)
        sm_mr[(mt * 16 + q * 4 + reg) * XSTR + w * 32 + nt * 16 + n] = f2bf(acc2[mt][nt][reg]);
  __syncthreads();

  // ---- GEMM3: gate logits = x.W1^T + mr.W2^T ----
  v4f acc3[2][2];
#pragma unroll
  for (int mt = 0; mt < 2; ++mt)
#pragma unroll
    for (int nt = 0; nt < 2; ++nt) { acc3[mt][nt][0]=0.f; acc3[mt][nt][1]=0.f; acc3[mt][nt][2]=0.f; acc3[mt][nt][3]=0.f; }

  for (int ki = 0; ki < 8; ++ki) {
    const int c0 = ki * 32 + q * 8;
    v8s xa[2], ma[2];
#pragma unroll
    for (int mt = 0; mt < 2; ++mt) {
      xa[mt] = *(const v8s*)&sm_xh[(mt * 16 + n) * XSTR + c0];
      ma[mt] = *(const v8s*)&sm_mr[(mt * 16 + n) * XSTR + c0];
    }
#pragma unroll
    for (int nt = 0; nt < 2; ++nt) {
      const int e = w * 32 + nt * 16 + n;
      v8s b1 = *(const v8s*)(W1b + e * DD + c0);
      v8s b2 = *(const v8s*)(W2b + e * DD + c0);
#pragma unroll
      for (int mt = 0; mt < 2; ++mt) {
        acc3[mt][nt] = __builtin_amdgcn_mfma_f32_16x16x32_bf16(xa[mt], b1, acc3[mt][nt], 0, 0, 0);
        acc3[mt][nt] = __builtin_amdgcn_mfma_f32_16x16x32_bf16(ma[mt], b2, acc3[mt][nt], 0, 0, 0);
      }
    }
  }

  // ---- epilogue: enhanced = x + sigmoid(logit + bg) * mr ----
#pragma unroll
  for (int nt = 0; nt < 2; ++nt) {
    const int col = w * 32 + nt * 16 + n;
    const float bgv = bg[col];
#pragma unroll
    for (int mt = 0; mt < 2; ++mt)
#pragma unroll
      for (int reg = 0; reg < 4; ++reg) {
        const int row = mt * 16 + q * 4 + reg;
        float z = acc3[mt][nt][reg] + bgv;
        float g = 1.0f / (1.0f + __expf(-z));
        float xv = bf2f(sm_xh[row * XSTR + col]);
        float mv = bf2f(sm_mr[row * XSTR + col]);
        out_e[(R0 + row) * (long)DD + col] = xv + g * mv;
      }
  }
}

extern "C" void kernel_launch(void* const* d_in, const int* in_sizes, int n_in,
                              void* d_out, int out_size, void* d_ws, size_t ws_size,
                              hipStream_t stream) {
  const float* x   = (const float*)d_in[0];
  const float* mem = (const float*)d_in[1];
  const float* Wg  = (const float*)d_in[2];
  const float* bg  = (const float*)d_in[3];

  unsigned short* mh  = (unsigned short*)d_ws;          // 512*256
  unsigned short* ml  = mh  + 131072;                   // 512*256
  unsigned short* mT  = ml  + 131072;                   // 256*512
  unsigned short* W1b = mT  + 131072;                   // 256*256
  unsigned short* W2b = W1b + 65536;                    // 256*256  (total ws: 1 MiB)

  float* out_e = (float*)d_out;                         // (32,4096,256)
  float* out_w = out_e + (long)ROWS * DD;               // (32,4096,512)

  vm_prep<<<512, 256, 0, stream>>>(mem, Wg, mh, ml, mT, W1b, W2b);
  vm_sim<<<4096, 512, 0, stream>>>(x, mh, ml, out_w);
  vm_rd<<<4096, 512, 0, stream>>>(x, bg, mT, W1b, W2b, out_w, out_e);
}

// Round 10
// 655.193 us; speedup vs baseline: 1.5575x; 1.5575x over previous
//
#include <hip/hip_runtime.h>

#define ROWS 131072
#define DD   256
#define MM   512
#define XSTR 264   // x/mr tile row stride (shorts): 256 + 8 pad
#define PSTR 520   // P tile row stride (shorts): 512 + 8 pad

typedef __attribute__((ext_vector_type(8))) short v8s;
typedef __attribute__((ext_vector_type(4))) float v4f;

static __device__ __forceinline__ unsigned short f2bf(float f) {
  union { float f; unsigned int u; } c; c.f = f;
  unsigned int u = c.u;
  return (unsigned short)((u + 0x7fffu + ((u >> 16) & 1u)) >> 16);  // RNE
}
static __device__ __forceinline__ float bf2f(unsigned short h) {
  union { float f; unsigned int u; } c; c.u = ((unsigned int)h) << 16;
  return c.f;
}

// Prep: write all B tables FRAGMENT-MAJOR so every in-kernel B load is one coalesced
// 1KB wave read (lane*16B), not 16 scattered 64B segments (R8 diagnosis: TA-bound gathers).
// Layout: tbl[colTile][ki][lane=q*16+n][j=0..7], element (row r, k) -> colTile=r/16, n=r%16,
// ki=k/32, q=(k%32)/8, j=k%8.
//   mhf/mlf: mem hi/lo,  [32][8][64][8]   (colTile stride 4096)
//   mtf:     mem^T hi,   [16][16][64][8]  (colTile stride 8192)
//   w1f/w2f: W1/W2,      [16][8][64][8]   (colTile stride 4096)
__global__ void vm_prep(const float* __restrict__ mem, const float* __restrict__ Wg,
                        unsigned short* __restrict__ mhf, unsigned short* __restrict__ mlf,
                        unsigned short* __restrict__ mtf, unsigned short* __restrict__ w1f,
                        unsigned short* __restrict__ w2f) {
  int i = blockIdx.x * 256 + threadIdx.x;  // 0..131071
  float v = mem[i];
  unsigned short h = f2bf(v);
  unsigned short l = f2bf(v - bf2f(h));
  {
    int r = i >> 8, k = i & 255;           // mem[r][k]: B for GEMM1 (col=r, K=k)
    int fidx = (r >> 4) * 4096 + (k >> 5) * 512 + (((k >> 3) & 3) * 16 + (r & 15)) * 8 + (k & 7);
    mhf[fidx] = h;
    mlf[fidx] = l;
  }
  {
    int m = i >> 8, d = i & 255;           // mem^T[d][m]: B for GEMM2 (col=d, K=m)
    int fidx = (d >> 4) * 8192 + (m >> 5) * 512 + (((m >> 3) & 3) * 16 + (d & 15)) * 8 + (m & 7);
    mtf[fidx] = h;
  }
  {
    float wv = Wg[i];
    int e = i >> 9, c = i & 511;
    unsigned short wb = f2bf(wv);
    int k = (c < DD) ? c : (c - DD);       // W[e][k]: B for GEMM3 (col=e, K=k)
    int fidx = (e >> 4) * 4096 + (k >> 5) * 512 + (((k >> 3) & 3) * 16 + (e & 15)) * 8 + (k & 7);
    if (c < DD) w1f[fidx] = wb;
    else        w2f[fidx] = wb;
  }
}

// Fused: sim(split-bf16 MFMA) -> softmax -> weights out -> P.mem -> gate -> enhanced out.
// Block = 512 thr (8 waves), 32 rows/block. GEMM1: wave w owns sim cols [w*64, w*64+64).
// GEMM2/3: wave w owns d/e cols [w*32, w*32+32).
// Structure = R4 (540us baseline) with ONE change: all B-operand loads go through the
// fragment-major tables (coalesced lane*16B), attacking the TA-gather bottleneck.
// NOTE: out_e uses a PLAIN store (NT on out_e failed post-timing re-poison, Round 3).
__global__ __launch_bounds__(512, 4) void vm_main(
    const float* __restrict__ x, const float* __restrict__ bg,
    const unsigned short* __restrict__ mhf, const unsigned short* __restrict__ mlf,
    const unsigned short* __restrict__ mtf, const unsigned short* __restrict__ w1f,
    const unsigned short* __restrict__ w2f,
    float* __restrict__ out_e, float* __restrict__ out_w)
{
  __shared__ __align__(16) unsigned short sm_xh[32 * XSTR];
  __shared__ __align__(16) unsigned short sm_u [32 * PSTR];  // union: xl (XSTR) / P (PSTR) / mr (XSTR)
  __shared__ __align__(16) float sm_max[32 * 8];
  __shared__ __align__(16) float sm_sum[32 * 8];
  unsigned short* sm_xl = sm_u;
  unsigned short* sm_p  = sm_u;
  unsigned short* sm_mr = sm_u;

  const int tid  = threadIdx.x;
  const int w    = tid >> 6;        // 0..7
  const int lane = tid & 63;
  const int q    = lane >> 4;
  const int n    = lane & 15;
  const long R0  = (long)blockIdx.x * 32;

  // ---- stage x tile rows R0..R0+31 as bf16 hi/lo in LDS ----
  {
    const int row = tid >> 4;            // 0..31
    const int g   = tid & 15;            // 16 threads/row, 16 cols each
    const float* xr = x + (R0 + row) * (long)DD;
    const int c0 = g * 16;
    float4 a0 = *(const float4*)(xr + c0);
    float4 a1 = *(const float4*)(xr + c0 + 4);
    float4 a2 = *(const float4*)(xr + c0 + 8);
    float4 a3 = *(const float4*)(xr + c0 + 12);
    float vv[16] = {a0.x,a0.y,a0.z,a0.w, a1.x,a1.y,a1.z,a1.w,
                    a2.x,a2.y,a2.z,a2.w, a3.x,a3.y,a3.z,a3.w};
    v8s hv0, lv0, hv1, lv1;
#pragma unroll
    for (int j = 0; j < 8; ++j) {
      unsigned short h = f2bf(vv[j]);
      hv0[j] = (short)h;
      lv0[j] = (short)f2bf(vv[j] - bf2f(h));
      unsigned short h2 = f2bf(vv[j + 8]);
      hv1[j] = (short)h2;
      lv1[j] = (short)f2bf(vv[j + 8] - bf2f(h2));
    }
    *(v8s*)&sm_xh[row * XSTR + c0]     = hv0;
    *(v8s*)&sm_xh[row * XSTR + c0 + 8] = hv1;
    *(v8s*)&sm_xl[row * XSTR + c0]     = lv0;
    *(v8s*)&sm_xl[row * XSTR + c0 + 8] = lv1;
  }
  __syncthreads();

  // ---- GEMM1: S[32 x 64(cols of this wave)] = x . mem^T, 3-term bf16 split ----
  v4f acc[2][4];
#pragma unroll
  for (int mt = 0; mt < 2; ++mt)
#pragma unroll
    for (int nt = 0; nt < 4; ++nt) { acc[mt][nt][0]=0.f; acc[mt][nt][1]=0.f; acc[mt][nt][2]=0.f; acc[mt][nt][3]=0.f; }

  for (int ki = 0; ki < 8; ++ki) {
    const int c0 = ki * 32 + q * 8;
    v8s ah[2], al[2];
#pragma unroll
    for (int mt = 0; mt < 2; ++mt) {
      ah[mt] = *(const v8s*)&sm_xh[(mt * 16 + n) * XSTR + c0];
      al[mt] = *(const v8s*)&sm_xl[(mt * 16 + n) * XSTR + c0];
    }
#pragma unroll
    for (int nt = 0; nt < 4; ++nt) {
      const int fb = ((w * 4 + nt) * 8 + ki) * 512 + lane * 8;   // coalesced fragment base
      v8s bh = *(const v8s*)(mhf + fb);
      v8s bl = *(const v8s*)(mlf + fb);
#pragma unroll
      for (int mt = 0; mt < 2; ++mt) {
        acc[mt][nt] = __builtin_amdgcn_mfma_f32_16x16x32_bf16(ah[mt], bh, acc[mt][nt], 0, 0, 0);
        acc[mt][nt] = __builtin_amdgcn_mfma_f32_16x16x32_bf16(al[mt], bh, acc[mt][nt], 0, 0, 0);
        acc[mt][nt] = __builtin_amdgcn_mfma_f32_16x16x32_bf16(ah[mt], bl, acc[mt][nt], 0, 0, 0);
      }
    }
  }

  // ---- softmax over M=512 (wave-partial -> shuffle over n -> LDS cross-wave) ----
  // C layout: row = mt*16 + q*4 + reg, col = w*64 + nt*16 + n
  float rmax[2][4];
#pragma unroll
  for (int mt = 0; mt < 2; ++mt)
#pragma unroll
    for (int reg = 0; reg < 4; ++reg) {
      float mval = acc[mt][0][reg];
#pragma unroll
      for (int nt = 1; nt < 4; ++nt) mval = fmaxf(mval, acc[mt][nt][reg]);
      rmax[mt][reg] = mval;
    }
#pragma unroll
  for (int off = 1; off < 16; off <<= 1)
#pragma unroll
    for (int mt = 0; mt < 2; ++mt)
#pragma unroll
      for (int reg = 0; reg < 4; ++reg)
        rmax[mt][reg] = fmaxf(rmax[mt][reg], __shfl_xor(rmax[mt][reg], off, 64));
  if (n == 0) {
#pragma unroll
    for (int mt = 0; mt < 2; ++mt)
#pragma unroll
      for (int reg = 0; reg < 4; ++reg)
        sm_max[(mt * 16 + q * 4 + reg) * 8 + w] = rmax[mt][reg];
  }
  __syncthreads();   // also: all GEMM1 reads of sm_xl complete past this point
  float gmax[2][4];
#pragma unroll
  for (int mt = 0; mt < 2; ++mt)
#pragma unroll
    for (int reg = 0; reg < 4; ++reg) {
      v4f r4 = *(const v4f*)&sm_max[(mt * 16 + q * 4 + reg) * 8];
      v4f r5 = *(const v4f*)&sm_max[(mt * 16 + q * 4 + reg) * 8 + 4];
      gmax[mt][reg] = fmaxf(fmaxf(fmaxf(r4[0], r4[1]), fmaxf(r4[2], r4[3])),
                            fmaxf(fmaxf(r5[0], r5[1]), fmaxf(r5[2], r5[3])));
    }
  float rsum[2][4];
#pragma unroll
  for (int mt = 0; mt < 2; ++mt)
#pragma unroll
    for (int reg = 0; reg < 4; ++reg) rsum[mt][reg] = 0.f;
#pragma unroll
  for (int mt = 0; mt < 2; ++mt)
#pragma unroll
    for (int nt = 0; nt < 4; ++nt)
#pragma unroll
      for (int reg = 0; reg < 4; ++reg) {
        float p = __expf(acc[mt][nt][reg] - gmax[mt][reg]);
        acc[mt][nt][reg] = p;
        rsum[mt][reg] += p;
      }
#pragma unroll
  for (int off = 1; off < 16; off <<= 1)
#pragma unroll
    for (int mt = 0; mt < 2; ++mt)
#pragma unroll
      for (int reg = 0; reg < 4; ++reg)
        rsum[mt][reg] += __shfl_xor(rsum[mt][reg], off, 64);
  if (n == 0) {
#pragma unroll
    for (int mt = 0; mt < 2; ++mt)
#pragma unroll
      for (int reg = 0; reg < 4; ++reg)
        sm_sum[(mt * 16 + q * 4 + reg) * 8 + w] = rsum[mt][reg];
  }
  __syncthreads();
  float ginv[2][4];
#pragma unroll
  for (int mt = 0; mt < 2; ++mt)
#pragma unroll
    for (int reg = 0; reg < 4; ++reg) {
      v4f s4 = *(const v4f*)&sm_sum[(mt * 16 + q * 4 + reg) * 8];
      v4f s5 = *(const v4f*)&sm_sum[(mt * 16 + q * 4 + reg) * 8 + 4];
      ginv[mt][reg] = 1.0f / (s4[0] + s4[1] + s4[2] + s4[3] + s5[0] + s5[1] + s5[2] + s5[3]);
    }

  // normalize: NT-store weights (268MB stream, never re-read), write bf16 P to LDS (PSTR)
#pragma unroll
  for (int mt = 0; mt < 2; ++mt)
#pragma unroll
    for (int nt = 0; nt < 4; ++nt) {
      const int col = w * 64 + nt * 16 + n;
#pragma unroll
      for (int reg = 0; reg < 4; ++reg) {
        float pv = acc[mt][nt][reg] * ginv[mt][reg];
        const int row = mt * 16 + q * 4 + reg;
        __builtin_nontemporal_store(pv, &out_w[(R0 + row) * (long)MM + col]);
        sm_p[row * PSTR + col] = f2bf(pv);
      }
    }
  __syncthreads();

  // ---- GEMM2: mr[32 x 32(d of this wave)] = P . mem, single K=512 pass ----
  v4f acc2[2][2];
#pragma unroll
  for (int mt = 0; mt < 2; ++mt)
#pragma unroll
    for (int nt = 0; nt < 2; ++nt) { acc2[mt][nt][0]=0.f; acc2[mt][nt][1]=0.f; acc2[mt][nt][2]=0.f; acc2[mt][nt][3]=0.f; }

  for (int ki = 0; ki < 16; ++ki) {
    const int c0 = ki * 32 + q * 8;
    v8s pa[2];
#pragma unroll
    for (int mt = 0; mt < 2; ++mt)
      pa[mt] = *(const v8s*)&sm_p[(mt * 16 + n) * PSTR + c0];
#pragma unroll
    for (int nt = 0; nt < 2; ++nt) {
      const int fb = ((w * 2 + nt) * 16 + ki) * 512 + lane * 8;  // coalesced fragment base
      v8s bt = *(const v8s*)(mtf + fb);
#pragma unroll
      for (int mt = 0; mt < 2; ++mt)
        acc2[mt][nt] = __builtin_amdgcn_mfma_f32_16x16x32_bf16(pa[mt], bt, acc2[mt][nt], 0, 0, 0);
    }
  }

  // ---- stage mr (bf16) into the union buffer (XSTR layout) for GEMM3 A-operand ----
  __syncthreads();   // all GEMM2 P reads complete before overwriting sm_u as mr
#pragma unroll
  for (int mt = 0; mt < 2; ++mt)
#pragma unroll
    for (int nt = 0; nt < 2; ++nt)
#pragma unroll
      for (int reg = 0; reg < 4; ++reg)
        sm_mr[(mt * 16 + q * 4 + reg) * XSTR + w * 32 + nt * 16 + n] = f2bf(acc2[mt][nt][reg]);
  __syncthreads();

  // ---- GEMM3: gate logits = x.W1^T + mr.W2^T over e cols of this wave ----
  v4f acc3[2][2];
#pragma unroll
  for (int mt = 0; mt < 2; ++mt)
#pragma unroll
    for (int nt = 0; nt < 2; ++nt) { acc3[mt][nt][0]=0.f; acc3[mt][nt][1]=0.f; acc3[mt][nt][2]=0.f; acc3[mt][nt][3]=0.f; }

  for (int ki = 0; ki < 8; ++ki) {
    const int c0 = ki * 32 + q * 8;
    v8s xa[2], ma[2];
#pragma unroll
    for (int mt = 0; mt < 2; ++mt) {
      xa[mt] = *(const v8s*)&sm_xh[(mt * 16 + n) * XSTR + c0];
      ma[mt] = *(const v8s*)&sm_mr[(mt * 16 + n) * XSTR + c0];
    }
#pragma unroll
    for (int nt = 0; nt < 2; ++nt) {
      const int fb = ((w * 2 + nt) * 8 + ki) * 512 + lane * 8;   // coalesced fragment base
      v8s b1 = *(const v8s*)(w1f + fb);
      v8s b2 = *(const v8s*)(w2f + fb);
#pragma unroll
      for (int mt = 0; mt < 2; ++mt) {
        acc3[mt][nt] = __builtin_amdgcn_mfma_f32_16x16x32_bf16(xa[mt], b1, acc3[mt][nt], 0, 0, 0);
        acc3[mt][nt] = __builtin_amdgcn_mfma_f32_16x16x32_bf16(ma[mt], b2, acc3[mt][nt], 0, 0, 0);
      }
    }
  }

  // ---- epilogue: enhanced = x + sigmoid(logit + bg) * mr ----
#pragma unroll
  for (int nt = 0; nt < 2; ++nt) {
    const int col = w * 32 + nt * 16 + n;
    const float bgv = bg[col];
#pragma unroll
    for (int mt = 0; mt < 2; ++mt)
#pragma unroll
      for (int reg = 0; reg < 4; ++reg) {
        const int row = mt * 16 + q * 4 + reg;
        float z = acc3[mt][nt][reg] + bgv;
        float g = 1.0f / (1.0f + __expf(-z));
        float xv = bf2f(sm_xh[row * XSTR + col]);   // xh only: |err| <= 2^-9 |x| << thr
        out_e[(R0 + row) * (long)DD + col] = xv + g * acc2[mt][nt][reg];
      }
  }
}

extern "C" void kernel_launch(void* const* d_in, const int* in_sizes, int n_in,
                              void* d_out, int out_size, void* d_ws, size_t ws_size,
                              hipStream_t stream) {
  const float* x   = (const float*)d_in[0];
  const float* mem = (const float*)d_in[1];
  const float* Wg  = (const float*)d_in[2];
  const float* bg  = (const float*)d_in[3];

  unsigned short* mhf = (unsigned short*)d_ws;          // 512*256 (fragment-major)
  unsigned short* mlf = mhf + 131072;                   // 512*256
  unsigned short* mtf = mlf + 131072;                   // 256*512
  unsigned short* w1f = mtf + 131072;                   // 256*256
  unsigned short* w2f = w1f + 65536;                    // 256*256  (total ws: 1 MiB)

  float* out_e = (float*)d_out;                         // (32,4096,256)
  float* out_w = out_e + (long)ROWS * DD;               // (32,4096,512)

  vm_prep<<<512, 256, 0, stream>>>(mem, Wg, mhf, mlf, mtf, w1f, w2f);
  vm_main<<<4096, 512, 0, stream>>>(x, bg, mhf, mlf, mtf, w1f, w2f, out_e, out_w);
}